// Round 1
// baseline (2210.409 us; speedup 1.0000x reference)
//
#include <hip/hip_runtime.h>
#include <math.h>

#define BB 4
#define SP 6272      // 28*28*8 spatial per batch
#define NSP 25088    // BB*SP
#define EPS 1e-5f

// ---------------- conv3d 3x3x3 pad1 + bias (+relu) (+BN stats) ----------------
// grid.x = 98 (98*256 == 25088 exactly), grid.y = COUT/OT. Thread = one spatial
// position, OT output channels in registers (x reused 8-9x per load). Weight
// addresses wave-uniform -> scalar loads. Padding: clamped offset * {0,1} mask.
template<int CIN, int COUT, int OT, bool RELU, bool STATS>
__global__ __launch_bounds__(256) void conv3x3(const float* __restrict__ X,
        const float* __restrict__ Wt, const float* __restrict__ bias,
        float* __restrict__ Y, float* __restrict__ s_sum, float* __restrict__ s_sq)
{
    int s = blockIdx.x * 256 + threadIdx.x;   // [0, NSP)
    int b = s / SP;
    int sp = s - b * SP;
    int d = sp / 224;
    int r = sp - d * 224;
    int h = r >> 3;
    int w = r & 7;
    int o0 = blockIdx.y * OT;

    int off[27]; float msk[27];
    #pragma unroll
    for (int t = 0; t < 27; t++) {
        int kd = t / 9 - 1, kh = (t / 3) % 3 - 1, kw = t % 3 - 1;
        int dd = d + kd, hh = h + kh, ww = w + kw;
        bool v = (unsigned)dd < 28u && (unsigned)hh < 28u && (unsigned)ww < 8u;
        off[t] = v ? (dd * 224 + hh * 8 + ww) : 0;
        msk[t] = v ? 1.f : 0.f;
    }
    float acc[OT];
    #pragma unroll
    for (int oo = 0; oo < OT; oo++) acc[oo] = bias[o0 + oo];

    const float* xb = X + (size_t)b * CIN * SP;
    for (int c = 0; c < CIN; c++) {
        const float* xc = xb + (size_t)c * SP;
        float xv[27];
        #pragma unroll
        for (int t = 0; t < 27; t++) xv[t] = xc[off[t]] * msk[t];
        #pragma unroll
        for (int oo = 0; oo < OT; oo++) {
            const float* wp = Wt + ((size_t)(o0 + oo) * CIN + c) * 27;
            #pragma unroll
            for (int t = 0; t < 27; t++) acc[oo] = fmaf(xv[t], wp[t], acc[oo]);
        }
    }
    #pragma unroll
    for (int oo = 0; oo < OT; oo++) {
        float v = acc[oo];
        if (RELU) v = fmaxf(v, 0.f);
        Y[((size_t)b * COUT + o0 + oo) * SP + sp] = v;
        if (STATS) {
            float rs = v, rq = v * v;
            #pragma unroll
            for (int ofs = 32; ofs > 0; ofs >>= 1) {
                rs += __shfl_down(rs, ofs, 64);
                rq += __shfl_down(rq, ofs, 64);
            }
            if ((threadIdx.x & 63) == 0) {
                atomicAdd(&s_sum[o0 + oo], rs);
                atomicAdd(&s_sq[o0 + oo], rq);
            }
        }
    }
}

// ---------------- BN apply (training-mode, biased var), in-place ----------------
// WRT: also write channel-minor transpose h3t[b][sp][c] for the deform gather.
template<bool WRT>
__global__ __launch_bounds__(256) void bn_apply(float* __restrict__ Y,
        const float* __restrict__ s_sum, const float* __restrict__ s_sq,
        const float* __restrict__ g, const float* __restrict__ bb,
        int C, float* __restrict__ Yt)
{
    int idx = blockIdx.x * 256 + threadIdx.x;
    int sp = idx % SP;
    int bc = idx / SP;
    int c = bc % C;
    int b = bc / C;
    float m  = s_sum[c] * (1.f / NSP);
    float v  = s_sq[c] * (1.f / NSP) - m * m;
    float sc = g[c] * rsqrtf(v + EPS);
    float val = (Y[idx] - m) * sc + bb[c];
    Y[idx] = val;
    if (WRT) Yt[((size_t)b * SP + sp) * 128 + c] = val;
}

// ---------------- deform weight transpose: dw[o][c][n] -> dwt[n][c][o] ----------------
__global__ __launch_bounds__(256) void transpose_dw(const float* __restrict__ dw,
                                                    float* __restrict__ dwt)
{
    int idx = blockIdx.x * 256 + threadIdx.x;   // 27*128*128 = 442368 = 1728*256
    int n = idx / 16384;
    int r = idx % 16384;
    int c = r >> 7;
    int o = r & 127;
    dwt[idx] = dw[((size_t)o * 128 + c) * 27 + n];
}

// ---------------- deformable conv + bias + relu + pooled/stat accumulation ----------------
// Block = (b, d, h): 8 w-positions x 128 output channels. y4 never materialized.
__global__ __launch_bounds__(256) void deform_pool(const float* __restrict__ Ht,
        const float* __restrict__ OFF, const float* __restrict__ dwt,
        const float* __restrict__ db, float* __restrict__ pooledraw,
        float* __restrict__ sumsq4)
{
    __shared__ int   idx_s[27][8][8];
    __shared__ float g_s[27][8][8];
    __shared__ __align__(16) float Vb[128 * 12];   // [c][w] padded to 12 (16B-aligned rows)
    __shared__ float red[512];

    int t = threadIdx.x;
    int b = blockIdx.y;
    int d = blockIdx.x / 28, h = blockIdx.x % 28;

    if (t < 216) {  // geometry for (n, w)
        int n = t >> 3, w = t & 7;
        int kd = n / 9 - 1, kh = (n / 3) % 3 - 1, kw = n % 3 - 1;
        size_t obase = (size_t)b * 81 * SP + d * 224 + h * 8 + w;
        float od = OFF[obase + (size_t)n * SP];
        float oh = OFF[obase + (size_t)(27 + n) * SP];
        float owv = OFF[obase + (size_t)(54 + n) * SP];
        float pd = fminf(fmaxf((float)(d + 1 + kd) + od, 0.f), 29.f);
        float ph = fminf(fmaxf((float)(h + 1 + kh) + oh, 0.f), 29.f);
        float pw = fminf(fmaxf((float)(w + 1 + kw) + owv, 0.f), 9.f);
        float qd = fminf(floorf(pd), 28.f);
        float qh = fminf(floorf(ph), 28.f);
        float qw = fminf(floorf(pw), 8.f);
        float td = fminf(pd - qd, 1.f);
        float th = fminf(ph - qh, 1.f);
        float tw = fminf(pw - qw, 1.f);
        int iqd = (int)qd - 1, iqh = (int)qh - 1, iqw = (int)qw - 1;  // unpadded corner 0
        #pragma unroll
        for (int cr = 0; cr < 8; cr++) {
            int i = cr >> 2, j = (cr >> 1) & 1, k = cr & 1;
            int du = iqd + i, hu = iqh + j, wu = iqw + k;
            bool val = (unsigned)du < 28u && (unsigned)hu < 28u && (unsigned)wu < 8u;
            float gg = (i ? td : 1.f - td) * (j ? th : 1.f - th) * (k ? tw : 1.f - tw);
            idx_s[n][w][cr] = val ? (du * 224 + hu * 8 + wu) : -1;
            g_s[n][w][cr] = gg;
        }
    }

    int lane_c = t & 127;     // phase2: channel; phase3: output channel o
    int wh = t >> 7;          // 0/1 -> w half
    float acc0 = 0.f, acc1 = 0.f, acc2 = 0.f, acc3 = 0.f;
    const float* hb = Ht + (size_t)b * SP * 128;

    for (int n = 0; n < 27; n++) {
        __syncthreads();
        // phase 2: V[c][w] = trilinear sample (coalesced across c)
        #pragma unroll
        for (int it = 0; it < 4; it++) {
            int w = wh * 4 + it;
            float v = 0.f;
            #pragma unroll
            for (int cr = 0; cr < 8; cr++) {
                int id = idx_s[n][w][cr];
                float gg = g_s[n][w][cr];
                float xv = (id >= 0) ? hb[(size_t)id * 128 + lane_c] : 0.f;
                v = fmaf(gg, xv, v);
            }
            Vb[lane_c * 12 + w] = v;
        }
        __syncthreads();
        // phase 3: out[o][w] += sum_c dwt[n][c][o] * V[c][w]
        const float* wp = dwt + (size_t)n * 16384 + lane_c;
        #pragma unroll 4
        for (int c = 0; c < 128; c++) {
            float wv = wp[(size_t)c * 128];
            float4 vv = *reinterpret_cast<const float4*>(&Vb[c * 12 + wh * 4]);
            acc0 = fmaf(wv, vv.x, acc0);
            acc1 = fmaf(wv, vv.y, acc1);
            acc2 = fmaf(wv, vv.z, acc2);
            acc3 = fmaf(wv, vv.w, acc3);
        }
    }

    int o = lane_c;
    float bo = db[o];
    float v0 = fmaxf(acc0 + bo, 0.f), v1 = fmaxf(acc1 + bo, 0.f);
    float v2 = fmaxf(acc2 + bo, 0.f), v3 = fmaxf(acc3 + bo, 0.f);
    float ps = v0 + v1 + v2 + v3;
    float pq = v0 * v0 + v1 * v1 + v2 * v2 + v3 * v3;
    __syncthreads();
    red[t] = ps; red[256 + t] = pq;
    __syncthreads();
    if (t < 128) {
        float s = red[t] + red[t + 128];
        float q = red[256 + t] + red[256 + t + 128];
        atomicAdd(&pooledraw[b * 128 + o], s);
        atomicAdd(&sumsq4[o], q);
    }
}

// ---------------- BN4-folded pooling + FC + log_softmax ----------------
__global__ __launch_bounds__(256) void final_head(const float* __restrict__ pooledraw,
        const float* __restrict__ sumsq4, const float* __restrict__ g4,
        const float* __restrict__ b4, const float* __restrict__ fcw,
        const float* __restrict__ fcb, float* __restrict__ out)
{
    __shared__ float pooled_s[4][128];
    __shared__ float logits[4][10];
    int t = threadIdx.x;
    if (t < 128) {
        float s0 = pooledraw[t], s1 = pooledraw[128 + t];
        float s2 = pooledraw[256 + t], s3 = pooledraw[384 + t];
        float tot = s0 + s1 + s2 + s3;
        float m  = tot * (1.f / NSP);
        float v  = sumsq4[t] * (1.f / NSP) - m * m;
        float sc = g4[t] * rsqrtf(v + EPS);
        float sh = b4[t] - m * sc;
        pooled_s[0][t] = s0 * (1.f / SP) * sc + sh;
        pooled_s[1][t] = s1 * (1.f / SP) * sc + sh;
        pooled_s[2][t] = s2 * (1.f / SP) * sc + sh;
        pooled_s[3][t] = s3 * (1.f / SP) * sc + sh;
    }
    __syncthreads();
    if (t < 40) {
        int b = t / 10, j = t % 10;
        float l = fcb[j];
        for (int c = 0; c < 128; c++) l = fmaf(pooled_s[b][c], fcw[j * 128 + c], l);
        logits[b][j] = l;
    }
    __syncthreads();
    if (t < 4) {
        float mx = -1e30f;
        for (int j = 0; j < 10; j++) mx = fmaxf(mx, logits[t][j]);
        float se = 0.f;
        for (int j = 0; j < 10; j++) se += expf(logits[t][j] - mx);
        float lse = mx + logf(se);
        for (int j = 0; j < 10; j++) out[t * 10 + j] = logits[t][j] - lse;
    }
}

extern "C" void kernel_launch(void* const* d_in, const int* in_sizes, int n_in,
                              void* d_out, int out_size, void* d_ws, size_t ws_size,
                              hipStream_t stream)
{
    (void)in_sizes; (void)n_in; (void)out_size; (void)ws_size;
    const float* x   = (const float*)d_in[0];
    const float* c1w = (const float*)d_in[1];
    const float* c1b = (const float*)d_in[2];
    const float* g1  = (const float*)d_in[3];
    const float* b1  = (const float*)d_in[4];
    const float* c2w = (const float*)d_in[5];
    const float* c2b = (const float*)d_in[6];
    const float* g2  = (const float*)d_in[7];
    const float* b2  = (const float*)d_in[8];
    const float* c3w = (const float*)d_in[9];
    const float* c3b = (const float*)d_in[10];
    const float* g3  = (const float*)d_in[11];
    const float* b3  = (const float*)d_in[12];
    const float* ow  = (const float*)d_in[13];
    const float* ob  = (const float*)d_in[14];
    const float* dw  = (const float*)d_in[15];
    const float* db  = (const float*)d_in[16];
    const float* g4  = (const float*)d_in[17];
    const float* b4  = (const float*)d_in[18];
    const float* fcw = (const float*)d_in[19];
    const float* fcb = (const float*)d_in[20];

    float* ws = (float*)d_ws;
    // stats block (memset to 0 each call), all < 2048 floats
    float* S1 = ws + 0,   *Q1 = ws + 32;
    float* S2 = ws + 96,  *Q2 = ws + 160;
    float* S3 = ws + 224, *Q3 = ws + 352;
    float* PO = ws + 480;   // 4*128
    float* Q4 = ws + 992;   // 128
    float* y1  = ws + 2048;            // 4*32*6272
    float* y2  = y1 + 802816;          // 4*64*6272
    float* y3  = y2 + 1605632;         // 4*128*6272
    float* h3t = y3 + 3211264;         // channel-minor copy of h3
    float* dwt = h3t + 3211264;        // 27*128*128
    // total ws use: ~9.28M floats = 37.1 MB

    float* outf = (float*)d_out;
    float* offs = outf + 40;           // second output: offsets (4,81,28,28,8)

    hipMemsetAsync(ws, 0, 2048 * sizeof(float), stream);
    transpose_dw<<<1728, 256, 0, stream>>>(dw, dwt);

    conv3x3<1, 32, 8, true, true><<<dim3(98, 4), 256, 0, stream>>>(x, c1w, c1b, y1, S1, Q1);
    bn_apply<false><<<3136, 256, 0, stream>>>(y1, S1, Q1, g1, b1, 32, nullptr);

    conv3x3<32, 64, 8, true, true><<<dim3(98, 8), 256, 0, stream>>>(y1, c2w, c2b, y2, S2, Q2);
    bn_apply<false><<<6272, 256, 0, stream>>>(y2, S2, Q2, g2, b2, 64, nullptr);

    conv3x3<64, 128, 8, true, true><<<dim3(98, 16), 256, 0, stream>>>(y2, c3w, c3b, y3, S3, Q3);
    bn_apply<true><<<12544, 256, 0, stream>>>(y3, S3, Q3, g3, b3, 128, h3t);

    conv3x3<128, 81, 9, false, false><<<dim3(98, 9), 256, 0, stream>>>(y3, ow, ob, offs,
                                                                        nullptr, nullptr);
    deform_pool<<<dim3(784, 4), 256, 0, stream>>>(h3t, offs, dwt, db, PO, Q4);
    final_head<<<1, 256, 0, stream>>>(PO, Q4, g4, b4, fcw, fcb, outf);
}